// Round 14
// baseline (248.828 us; speedup 1.0000x reference)
//
#include <hip/hip_runtime.h>

#define DIM 128
#define PAD 64

typedef __bf16 bf16x8 __attribute__((ext_vector_type(8)));
typedef float f32x4 __attribute__((ext_vector_type(4)));
typedef unsigned short ushort8 __attribute__((ext_vector_type(8)));

__device__ __forceinline__ unsigned short f2bf(float f) {
    union { float f; unsigned u; } x; x.f = f;
    unsigned r = x.u + 0x7FFF + ((x.u >> 16) & 1);   // RNE
    return (unsigned short)(r >> 16);
}

__device__ __forceinline__ float bf2f(unsigned short u) {
    union { unsigned u; float f; } x; x.u = ((unsigned)u) << 16;
    return x.f;
}

// ---------- fused build: edge scatter (atomic-latency-bound) + conv/pack.
// R11 post-mortem: 4x scatter unroll REGRESSED (57->66us; deeper coherent-point
// queueing, occupancy up but contention dominates) -> scalar scatter restored.
// NOTE: nontemporal store REQUIRED for correctness (R12): normal 4B stores to one 64B
// col_pad line from blocks on different XCDs -> partially-dirty non-coherent L2 copies
// -> writeback clobbers other XCDs' bytes. nt bypasses L2 -> byte-granular HBM writes.
// R3: atomicExch did NOT reduce WRITE_SIZE and was +16us slower. nt store kept.
__global__ void build_fused(const int* __restrict__ src, const int* __restrict__ dst,
                            int* __restrict__ counts, int* __restrict__ col_pad,
                            const float* __restrict__ x, unsigned short* __restrict__ xb,
                            const float* __restrict__ W_self, const float* __restrict__ W_neigh,
                            unsigned short* __restrict__ Bp, int E, int n8) {
    int t = blockIdx.x * blockDim.x + threadIdx.x;
    if (t < E) {
        int v = dst[t];
        int pos = atomicAdd(&counts[v], 1);
        if (pos < PAD)
            __builtin_nontemporal_store(src[t], &col_pad[(size_t)v * PAD + pos]);
    }
    if (t < n8) {
        const float4* p = (const float4*)(x + (size_t)t * 8);
        float4 a = p[0], b = p[1];
        ushort8 o = {f2bf(a.x), f2bf(a.y), f2bf(a.z), f2bf(a.w),
                     f2bf(b.x), f2bf(b.y), f2bf(b.z), f2bf(b.w)};
        *(ushort8*)(xb + (size_t)t * 8) = o;
    } else if (t < n8 + 3 * 64 * 64) {
        int u = t - n8;
        int lane = u & 63;
        int g = u >> 6;
        int l = g >> 6;
        int r = g & 63;
        int ns = r >> 3, ks = r & 7;
        const float* Wsl = W_self + (size_t)l * DIM * DIM;
        const float* Wnl = W_neigh + (size_t)l * DIM * DIM;
        unsigned short* dstp = Bp + (size_t)l * 32768 + ((size_t)(ns * 8 + ks) * 64 + lane) * 8;
        int nn = ns * 16 + (lane & 15);
        int kbase = ks * 32 + (lane >> 4) * 8;
        ushort8 o;
        #pragma unroll
        for (int j = 0; j < 8; ++j) {
            int k = kbase + j;
            float v = (k < 128) ? Wsl[(size_t)k * DIM + nn] : Wnl[(size_t)(k - 128) * DIM + nn];
            o[j] = f2bf(v);
        }
        *(ushort8*)dstp = o;
    }
}

// ---------- fused layer v7: v5 + 2-deep software-pipelined gather.
// Ledger: more waves (R5 null), wider burst (R3 neg), idx staging (R7 null),
// XCD pinning (R9 neg) -- all raised POTENTIAL parallelism. v5's loop drains
// vmcnt to 0 before every consume phase -> 0 lines in flight during ~128cy of
// VALU; measured sustained ~34 lines/CU vs queue limits far higher. This round:
// issue block i+1's 4 row loads BEFORE consuming block i (compiler emits
// vmcnt(4), loads span the FMA phase -> ~2x sustained in-flight). VGPR +~20
// -> launch_bounds (128,5); R5 proved 20 vs 24 waves/CU is free. ----------
__global__ __launch_bounds__(128, 5) void layer_k(
    const unsigned short* __restrict__ hb,
    const int* __restrict__ counts, const int* __restrict__ col_pad,
    const unsigned short* __restrict__ Bp, const float* __restrict__ bias,
    unsigned short* __restrict__ out_bf, float* __restrict__ out_f32,
    int n, int do_relu)
{
    __shared__ int ldsIdx[16 * PAD];               // 4096 B: block's index lists
    __shared__ int ldsCnt[16];
    __shared__ unsigned short ldsA[16 * 128];      // 4096 B: 16 x 128 bf16 agg tile

    const int tid  = threadIdx.x;
    const int w    = tid >> 6;     // 0..1
    const int lane = tid & 63;
    const int li   = lane & 15;    // 16B chunk idx (gather) / output row-in-16 (gemm)
    const int grp  = lane >> 4;    // node slot (gather) / k-quad (gemm)
    const int g    = w * 4 + grp;  // gather group id 0..7

    const int nb0 = blockIdx.x * 16;

    // ---- stage idx lists: 16 nodes x 64 ints = 4KB, contiguous in col_pad ----
    {
        const int4* s = (const int4*)(col_pad + (size_t)nb0 * PAD);
        int4* d = (int4*)ldsIdx;
        d[tid]       = s[tid];
        d[tid + 128] = s[tid + 128];
    }
    if (tid < 16) {
        const int node = nb0 + tid;
        ldsCnt[tid] = (node < n) ? counts[node] : 0;
    }
    __syncthreads();

    // ---- gather: each 16-lane group aggregates one node per round, 2 rounds;
    // 2-deep register pipeline: block i+1's loads issued before block i's FMAs ----
    #pragma unroll
    for (int r = 0; r < 2; ++r) {
        const int row = r * 8 + g;                 // 0..15 local row
        const int c   = ldsCnt[row];
        const int cc  = min(c, PAD);
        const int* cp = &ldsIdx[row * PAD];        // LDS; group-uniform -> broadcast
        float a[8] = {0.f, 0.f, 0.f, 0.f, 0.f, 0.f, 0.f, 0.f};

        if (cc > 0) {
            // LOADBLK(ii): issue 4 row loads for block at ii (clamped+masked)
            #define LOADBLK(ii, w0, w1, w2, w3, n1, n2, n3)                        \
                {                                                                   \
                    int4 uu = *(const int4*)(cp + (ii));                            \
                    const int rem = cc - (ii);                                      \
                    n1 = rem > 1 ? 1.f : 0.f;                                       \
                    n2 = rem > 2 ? 1.f : 0.f;                                       \
                    n3 = rem > 3 ? 1.f : 0.f;                                       \
                    const int q1 = rem > 1 ? uu.y : uu.x;                           \
                    const int q2 = rem > 2 ? uu.z : uu.x;                           \
                    const int q3 = rem > 3 ? uu.w : uu.x;                           \
                    w0 = *(const ushort8*)(hb + (size_t)uu.x * DIM + li * 8);       \
                    w1 = *(const ushort8*)(hb + (size_t)q1   * DIM + li * 8);       \
                    w2 = *(const ushort8*)(hb + (size_t)q2   * DIM + li * 8);       \
                    w3 = *(const ushort8*)(hb + (size_t)q3   * DIM + li * 8);       \
                }
            #define CONSUME(w0, w1, w2, w3, n1, n2, n3)                             \
                {                                                                   \
                    _Pragma("unroll")                                               \
                    for (int j = 0; j < 8; ++j)                                     \
                        a[j] += (bf2f(w0[j]) + n1 * bf2f(w1[j])) +                  \
                                (n2 * bf2f(w2[j]) + n3 * bf2f(w3[j]));              \
                }

            ushort8 v0, v1, v2, v3;
            float m1, m2, m3;
            LOADBLK(0, v0, v1, v2, v3, m1, m2, m3);
            int i = 0;
            for (; i + 4 < cc; i += 4) {
                ushort8 p0, p1, p2, p3;
                float k1, k2, k3;
                LOADBLK(i + 4, p0, p1, p2, p3, k1, k2, k3);   // next block in flight
                CONSUME(v0, v1, v2, v3, m1, m2, m3);          // waits vmcnt(4) only
                v0 = p0; v1 = p1; v2 = p2; v3 = p3;
                m1 = k1; m2 = k2; m3 = k3;
            }
            CONSUME(v0, v1, v2, v3, m1, m2, m3);              // epilogue block
            #undef LOADBLK
            #undef CONSUME
        }

        const float s = 1.0f / (float)(c > 0 ? c : 1);
        ushort8 o = {f2bf(a[0] * s), f2bf(a[1] * s), f2bf(a[2] * s), f2bf(a[3] * s),
                     f2bf(a[4] * s), f2bf(a[5] * s), f2bf(a[6] * s), f2bf(a[7] * s)};
        // swizzled store: logical chunk li of row -> slot li ^ (row&7)  (G4/T2)
        *(ushort8*)&ldsA[((size_t)row * 16 + (li ^ (row & 7))) * 8] = o;
    }
    __syncthreads();

    // ---- GEMM: wave w -> 16 rows x 64 cols (ns half w). B frags straight from
    // global (L2-resident, coalesced 1KB per frag per wave). ----
    const int nsb  = w * 4;
    const int row0 = nb0;
    int ar = row0 + li;
    if (ar >= n) ar = n - 1;                       // clamp; invalid rows never stored
    const unsigned short* hp = hb + (size_t)ar * DIM + grp * 8;
    const int arow = li;
    const int sw = arow & 7;

    f32x4 acc[4];
    #pragma unroll
    for (int nsi = 0; nsi < 4; ++nsi) acc[nsi] = (f32x4){0.f, 0.f, 0.f, 0.f};

    #pragma unroll
    for (int ks = 0; ks < 8; ++ks) {
        bf16x8 av;
        if (ks < 4) {
            av = *(const bf16x8*)(hp + ks * 32);
        } else {
            int ch = ((ks - 4) * 4 + grp) ^ sw;    // inverse of the gather swizzle
            av = *(const bf16x8*)&ldsA[((size_t)arow * 16 + ch) * 8];
        }
        #pragma unroll
        for (int nsi = 0; nsi < 4; ++nsi) {
            const int ns = nsb + nsi;
            bf16x8 b = *(const bf16x8*)(Bp + ((size_t)(ns * 8 + ks) * 64 + lane) * 8);
            acc[nsi] = __builtin_amdgcn_mfma_f32_16x16x32_bf16(av, b, acc[nsi], 0, 0, 0);
        }
    }

    #pragma unroll
    for (int nsi = 0; nsi < 4; ++nsi) {
        int col = (nsb + nsi) * 16 + li;
        float bb = bias[col];
        #pragma unroll
        for (int r = 0; r < 4; ++r) {
            int gr = row0 + grp * 4 + r;
            if (gr < n) {
                float v = acc[nsi][r] + bb;
                if (do_relu) v = fmaxf(v, 0.f);
                if (out_bf) out_bf[(size_t)gr * DIM + col] = f2bf(v);
                else        out_f32[(size_t)gr * DIM + col] = v;
            }
        }
    }
}

// ---------- launch ----------

extern "C" void kernel_launch(void* const* d_in, const int* in_sizes, int n_in,
                              void* d_out, int out_size, void* d_ws, size_t ws_size,
                              hipStream_t stream) {
    const float* x      = (const float*)d_in[0];
    const int*   src    = (const int*)d_in[1];
    const int*   dst    = (const int*)d_in[2];
    const float* W_self = (const float*)d_in[3];
    const float* W_neigh= (const float*)d_in[4];
    const float* bias   = (const float*)d_in[5];
    float* out = (float*)d_out;

    const int n = in_sizes[0] / DIM;   // 50000
    const int e = in_sizes[1];         // 800000

    char* ws = (char*)d_ws;
    size_t off = 0;
    auto alloc = [&](size_t bytes) -> void* {
        void* p = ws + off;
        off += (bytes + 255) & ~(size_t)255;
        return p;
    };
    int*   counts  = (int*)alloc((size_t)n * 4);
    int*   col_pad = (int*)alloc((size_t)n * PAD * 4);
    unsigned short* x_bf  = (unsigned short*)alloc((size_t)n * DIM * 2);
    unsigned short* h_a   = (unsigned short*)alloc((size_t)n * DIM * 2);
    unsigned short* h_b   = (unsigned short*)alloc((size_t)n * DIM * 2);
    unsigned short* Bp    = (unsigned short*)alloc((size_t)3 * 32768 * 2);

    const int n8 = n * DIM / 8;         // 800000

    hipMemsetAsync(counts, 0, (size_t)n * 4, stream);
    const int build_units = (e > n8 + 3 * 64 * 64) ? e : (n8 + 3 * 64 * 64);
    build_fused<<<(build_units + 255) / 256, 256, 0, stream>>>(
        src, dst, counts, col_pad, x, x_bf, W_self, W_neigh, Bp, e, n8);

    const int layer_grid = (n + 15) / 16;   // 3125

    layer_k<<<layer_grid, 128, 0, stream>>>(x_bf, counts, col_pad, Bp, bias,
                                            h_a, nullptr, n, 1);
    layer_k<<<layer_grid, 128, 0, stream>>>(h_a, counts, col_pad, Bp + 32768, bias + DIM,
                                            h_b, nullptr, n, 1);
    layer_k<<<layer_grid, 128, 0, stream>>>(h_b, counts, col_pad, Bp + 2 * 32768, bias + 2 * DIM,
                                            nullptr, out, n, 0);
}

// Round 16
// 221.087 us; speedup vs baseline: 1.1255x; 1.1255x over previous
//
#include <hip/hip_runtime.h>

#define DIM 128
#define PAD 64

typedef __bf16 bf16x8 __attribute__((ext_vector_type(8)));
typedef float f32x4 __attribute__((ext_vector_type(4)));
typedef unsigned short ushort8 __attribute__((ext_vector_type(8)));
typedef float floatx2 __attribute__((ext_vector_type(2)));

__device__ __forceinline__ unsigned short f2bf(float f) {
    union { float f; unsigned u; } x; x.f = f;
    unsigned r = x.u + 0x7FFF + ((x.u >> 16) & 1);   // RNE
    return (unsigned short)(r >> 16);
}

__device__ __forceinline__ float bf2f(unsigned short u) {
    union { unsigned u; float f; } x; x.u = ((unsigned)u) << 16;
    return x.f;
}

__device__ __forceinline__ unsigned char f2fp8(float v) {
    int r = __builtin_amdgcn_cvt_pk_fp8_f32(v, v, 0, false);
    return (unsigned char)(r & 0xFF);
}

// ---------- fused build: edge scatter (atomic-latency-bound) + conv/pack.
// R11: 4x scatter unroll REGRESSED (57->66us, coherent-point queueing) -> scalar.
// R3: atomicExch REGRESSED (+16us, WRITE_SIZE unchanged) -> nt store kept.
// NOTE: nontemporal store REQUIRED for correctness (R12): normal 4B stores to one
// 64B col_pad line from blocks on different XCDs -> partially-dirty non-coherent
// L2 copies -> writeback clobbers other XCDs' bytes. nt = byte-granular HBM writes.
// R15: pack phase additionally writes an fp8-e4m3 shadow of x for the gather.
__global__ void build_fused(const int* __restrict__ src, const int* __restrict__ dst,
                            int* __restrict__ counts, int* __restrict__ col_pad,
                            const float* __restrict__ x, unsigned short* __restrict__ xb,
                            unsigned char* __restrict__ xf8,
                            const float* __restrict__ W_self, const float* __restrict__ W_neigh,
                            unsigned short* __restrict__ Bp, int E, int n8) {
    int t = blockIdx.x * blockDim.x + threadIdx.x;
    if (t < E) {
        int v = dst[t];
        int pos = atomicAdd(&counts[v], 1);
        if (pos < PAD)
            __builtin_nontemporal_store(src[t], &col_pad[(size_t)v * PAD + pos]);
    }
    if (t < n8) {
        const float4* p = (const float4*)(x + (size_t)t * 8);
        float4 a = p[0], b = p[1];
        ushort8 o = {f2bf(a.x), f2bf(a.y), f2bf(a.z), f2bf(a.w),
                     f2bf(b.x), f2bf(b.y), f2bf(b.z), f2bf(b.w)};
        *(ushort8*)(xb + (size_t)t * 8) = o;
        int lo = 0, hi = 0;
        lo = __builtin_amdgcn_cvt_pk_fp8_f32(a.x, a.y, lo, false);
        lo = __builtin_amdgcn_cvt_pk_fp8_f32(a.z, a.w, lo, true);
        hi = __builtin_amdgcn_cvt_pk_fp8_f32(b.x, b.y, hi, false);
        hi = __builtin_amdgcn_cvt_pk_fp8_f32(b.z, b.w, hi, true);
        uint2 q = make_uint2((unsigned)lo, (unsigned)hi);
        *(uint2*)(xf8 + (size_t)t * 8) = q;
    } else if (t < n8 + 3 * 64 * 64) {
        int u = t - n8;
        int lane = u & 63;
        int g = u >> 6;
        int l = g >> 6;
        int r = g & 63;
        int ns = r >> 3, ks = r & 7;
        const float* Wsl = W_self + (size_t)l * DIM * DIM;
        const float* Wnl = W_neigh + (size_t)l * DIM * DIM;
        unsigned short* dstp = Bp + (size_t)l * 32768 + ((size_t)(ns * 8 + ks) * 64 + lane) * 8;
        int nn = ns * 16 + (lane & 15);
        int kbase = ks * 32 + (lane >> 4) * 8;
        ushort8 o;
        #pragma unroll
        for (int j = 0; j < 8; ++j) {
            int k = kbase + j;
            float v = (k < 128) ? Wsl[(size_t)k * DIM + nn] : Wnl[(size_t)(k - 128) * DIM + nn];
            o[j] = f2bf(v);
        }
        *(ushort8*)dstp = o;
    }
}

// ---------- fused layer v8: v5 structure (best measured, 243.5us) with the
// gather reading an fp8-e4m3 shadow of h. MLP-axis ledger CLOSED (5 nulls:
// R3/R5/R7/R9/R14) -> gather is line-transaction-bound at a SHARED ~52 lines/ns
// ceiling. Lever: lines/edge. fp8 rows = 128B = 2 lines (was 4); working set
// 6.4MB (was 12.8) -> higher L2/L3 residency. GEMM self-term + ldsA + MFMA
// stay bf16; only neighbor values are fp8-quantized (mean over ~16 averages
// the quantization noise). HW cvt_pk decode ~= bf16 shift cost. ----------
__global__ __launch_bounds__(128, 6) void layer_k(
    const unsigned short* __restrict__ hb, const unsigned char* __restrict__ h8,
    const int* __restrict__ counts, const int* __restrict__ col_pad,
    const unsigned short* __restrict__ Bp, const float* __restrict__ bias,
    unsigned short* __restrict__ out_bf, unsigned char* __restrict__ out_f8,
    float* __restrict__ out_f32, int n, int do_relu)
{
    __shared__ int ldsIdx[16 * PAD];               // 4096 B: block's index lists
    __shared__ int ldsCnt[16];
    __shared__ unsigned short ldsA[16 * 128];      // 4096 B: 16 x 128 bf16 agg tile

    const int tid  = threadIdx.x;
    const int w    = tid >> 6;     // 0..1
    const int lane = tid & 63;
    const int li   = lane & 15;    // 8B chunk idx (gather) / output row-in-16 (gemm)
    const int grp  = lane >> 4;    // node slot (gather) / k-quad (gemm)
    const int g    = w * 4 + grp;  // gather group id 0..7

    const int nb0 = blockIdx.x * 16;

    // ---- stage idx lists: 16 nodes x 64 ints = 4KB, contiguous in col_pad ----
    {
        const int4* s = (const int4*)(col_pad + (size_t)nb0 * PAD);
        int4* d = (int4*)ldsIdx;
        d[tid]       = s[tid];
        d[tid + 128] = s[tid + 128];
    }
    if (tid < 16) {
        const int node = nb0 + tid;
        ldsCnt[tid] = (node < n) ? counts[node] : 0;
    }
    __syncthreads();

    // ---- gather: each 16-lane group aggregates one node per round, 2 rounds.
    // Group reads full 128B fp8 rows (16 lanes x 8B), 4 neighbors/iter,
    // remainder by mask-FMA (indices clamped to a valid in-range value). ----
    #pragma unroll
    for (int r = 0; r < 2; ++r) {
        const int row = r * 8 + g;                 // 0..15 local row
        const int c   = ldsCnt[row];
        const int cc  = min(c, PAD);
        const int* cp = &ldsIdx[row * PAD];        // LDS; group-uniform -> broadcast
        float a[8] = {0.f, 0.f, 0.f, 0.f, 0.f, 0.f, 0.f, 0.f};
        for (int i = 0; i < cc; i += 4) {
            int4 uu = *(const int4*)(cp + i);
            const int rem = cc - i;                // >= 1
            const float m1 = rem > 1 ? 1.f : 0.f;
            const float m2 = rem > 2 ? 1.f : 0.f;
            const float m3 = rem > 3 ? 1.f : 0.f;
            const int u1 = rem > 1 ? uu.y : uu.x;  // clamp addr to a valid index
            const int u2 = rem > 2 ? uu.z : uu.x;
            const int u3 = rem > 3 ? uu.w : uu.x;
            uint2 d0 = *(const uint2*)(h8 + (size_t)uu.x * DIM + li * 8);
            uint2 d1 = *(const uint2*)(h8 + (size_t)u1   * DIM + li * 8);
            uint2 d2 = *(const uint2*)(h8 + (size_t)u2   * DIM + li * 8);
            uint2 d3 = *(const uint2*)(h8 + (size_t)u3   * DIM + li * 8);
            #define ACCUM(dd, mm)                                                   \
                {                                                                   \
                    floatx2 f0 = __builtin_amdgcn_cvt_pk_f32_fp8((int)dd.x, false); \
                    floatx2 f1 = __builtin_amdgcn_cvt_pk_f32_fp8((int)dd.x, true);  \
                    floatx2 f2 = __builtin_amdgcn_cvt_pk_f32_fp8((int)dd.y, false); \
                    floatx2 f3 = __builtin_amdgcn_cvt_pk_f32_fp8((int)dd.y, true);  \
                    a[0] += mm * f0.x; a[1] += mm * f0.y;                           \
                    a[2] += mm * f1.x; a[3] += mm * f1.y;                           \
                    a[4] += mm * f2.x; a[5] += mm * f2.y;                           \
                    a[6] += mm * f3.x; a[7] += mm * f3.y;                           \
                }
            ACCUM(d0, 1.0f)
            ACCUM(d1, m1)
            ACCUM(d2, m2)
            ACCUM(d3, m3)
            #undef ACCUM
        }
        const float s = 1.0f / (float)(c > 0 ? c : 1);
        ushort8 o = {f2bf(a[0] * s), f2bf(a[1] * s), f2bf(a[2] * s), f2bf(a[3] * s),
                     f2bf(a[4] * s), f2bf(a[5] * s), f2bf(a[6] * s), f2bf(a[7] * s)};
        // swizzled store: logical chunk li of row -> slot li ^ (row&7)  (G4/T2)
        *(ushort8*)&ldsA[((size_t)row * 16 + (li ^ (row & 7))) * 8] = o;
    }
    __syncthreads();

    // ---- GEMM: wave w -> 16 rows x 64 cols (ns half w). B frags straight from
    // global (L2-resident, coalesced 1KB per frag per wave). ----
    const int nsb  = w * 4;
    const int row0 = nb0;
    int ar = row0 + li;
    if (ar >= n) ar = n - 1;                       // clamp; invalid rows never stored
    const unsigned short* hp = hb + (size_t)ar * DIM + grp * 8;
    const int arow = li;
    const int sw = arow & 7;

    f32x4 acc[4];
    #pragma unroll
    for (int nsi = 0; nsi < 4; ++nsi) acc[nsi] = (f32x4){0.f, 0.f, 0.f, 0.f};

    #pragma unroll
    for (int ks = 0; ks < 8; ++ks) {
        bf16x8 av;
        if (ks < 4) {
            av = *(const bf16x8*)(hp + ks * 32);
        } else {
            int ch = ((ks - 4) * 4 + grp) ^ sw;    // inverse of the gather swizzle
            av = *(const bf16x8*)&ldsA[((size_t)arow * 16 + ch) * 8];
        }
        #pragma unroll
        for (int nsi = 0; nsi < 4; ++nsi) {
            const int ns = nsb + nsi;
            bf16x8 b = *(const bf16x8*)(Bp + ((size_t)(ns * 8 + ks) * 64 + lane) * 8);
            acc[nsi] = __builtin_amdgcn_mfma_f32_16x16x32_bf16(av, b, acc[nsi], 0, 0, 0);
        }
    }

    #pragma unroll
    for (int nsi = 0; nsi < 4; ++nsi) {
        int col = (nsb + nsi) * 16 + li;
        float bb = bias[col];
        #pragma unroll
        for (int r = 0; r < 4; ++r) {
            int gr = row0 + grp * 4 + r;
            if (gr < n) {
                float v = acc[nsi][r] + bb;
                if (do_relu) v = fmaxf(v, 0.f);
                if (out_bf) {
                    out_bf[(size_t)gr * DIM + col] = f2bf(v);
                    out_f8[(size_t)gr * DIM + col] = f2fp8(v);
                } else {
                    out_f32[(size_t)gr * DIM + col] = v;
                }
            }
        }
    }
}

// ---------- launch ----------

extern "C" void kernel_launch(void* const* d_in, const int* in_sizes, int n_in,
                              void* d_out, int out_size, void* d_ws, size_t ws_size,
                              hipStream_t stream) {
    const float* x      = (const float*)d_in[0];
    const int*   src    = (const int*)d_in[1];
    const int*   dst    = (const int*)d_in[2];
    const float* W_self = (const float*)d_in[3];
    const float* W_neigh= (const float*)d_in[4];
    const float* bias   = (const float*)d_in[5];
    float* out = (float*)d_out;

    const int n = in_sizes[0] / DIM;   // 50000
    const int e = in_sizes[1];         // 800000

    char* ws = (char*)d_ws;
    size_t off = 0;
    auto alloc = [&](size_t bytes) -> void* {
        void* p = ws + off;
        off += (bytes + 255) & ~(size_t)255;
        return p;
    };
    int*   counts  = (int*)alloc((size_t)n * 4);
    int*   col_pad = (int*)alloc((size_t)n * PAD * 4);
    unsigned short* x_bf  = (unsigned short*)alloc((size_t)n * DIM * 2);
    unsigned short* h_a   = (unsigned short*)alloc((size_t)n * DIM * 2);
    unsigned short* h_b   = (unsigned short*)alloc((size_t)n * DIM * 2);
    unsigned short* Bp    = (unsigned short*)alloc((size_t)3 * 32768 * 2);
    unsigned char*  f_x   = (unsigned char*)alloc((size_t)n * DIM);
    unsigned char*  f_a   = (unsigned char*)alloc((size_t)n * DIM);
    // f_b aliases x_bf: x_bf is dead after layer 0; f_b written layer 1, read
    // layer 2. Keeps total ws at the proven 64.4MB budget.
    unsigned char*  f_b   = (unsigned char*)x_bf;

    const int n8 = n * DIM / 8;         // 800000

    hipMemsetAsync(counts, 0, (size_t)n * 4, stream);
    const int build_units = (e > n8 + 3 * 64 * 64) ? e : (n8 + 3 * 64 * 64);
    build_fused<<<(build_units + 255) / 256, 256, 0, stream>>>(
        src, dst, counts, col_pad, x, x_bf, f_x, W_self, W_neigh, Bp, e, n8);

    const int layer_grid = (n + 15) / 16;   // 3125

    layer_k<<<layer_grid, 128, 0, stream>>>(x_bf, f_x, counts, col_pad, Bp, bias,
                                            h_a, f_a, nullptr, n, 1);
    layer_k<<<layer_grid, 128, 0, stream>>>(h_a, f_a, counts, col_pad, Bp + 32768, bias + DIM,
                                            h_b, f_b, nullptr, n, 1);
    layer_k<<<layer_grid, 128, 0, stream>>>(h_b, f_b, counts, col_pad, Bp + 2 * 32768,
                                            bias + 2 * DIM, nullptr, nullptr, out, n, 0);
}